// Round 1
// baseline (164.599 us; speedup 1.0000x reference)
//
#include <hip/hip_runtime.h>

#define K   5
#define KK  25
#define H   160
#define W   160
#define C   64
#define BS  4
#define HW  (H * W)
#define CPG 8           // channels per block (grid.y = C/CPG)
#define BLK 256

__global__ __launch_bounds__(BLK) void kconv_kernel(
    const float* __restrict__ fm,
    const float* __restrict__ kernel,
    const int*  __restrict__ dil,
    float* __restrict__ out)
{
    const int p  = blockIdx.x * BLK + threadIdx.x;   // pixel index in [0, HW)
    const int b  = blockIdx.z;
    const int cg = blockIdx.y;                       // channel group
    const int d  = dil[0];                           // dilation (1 in the bench)

    const int y = p / W;
    const int x = p - y * W;

    // Per-pixel weights, with torch.flip on the tap axis:
    //   out += kernel[b, 24 - (i*5+j), y, x] * fm[b, c, y+(i-2)*d, x+(j-2)*d]
    // OOB taps: weight zeroed, address clamped -> branch-free inner loop.
    const float* kb = kernel + (size_t)b * KK * HW + p;
    float wgt[KK];
    int   offs[KK];
#pragma unroll
    for (int i = 0; i < K; ++i) {
        const int yy  = y + (i - 2) * d;
        const bool yok = (yy >= 0) && (yy < H);
        const int yc  = min(max(yy, 0), H - 1);
#pragma unroll
        for (int j = 0; j < K; ++j) {
            const int xx  = x + (j - 2) * d;
            const bool ok = yok && (xx >= 0) && (xx < W);
            const int xc  = min(max(xx, 0), W - 1);
            const int t   = i * K + j;
            const float wv = kb[(size_t)(KK - 1 - t) * HW];
            wgt[t]  = ok ? wv : 0.0f;
            offs[t] = yc * W + xc;
        }
    }

    const float* fb = fm  + (size_t)b * C * HW + (size_t)cg * CPG * HW;
    float*       ob = out + (size_t)b * C * HW + (size_t)cg * CPG * HW + p;

#pragma unroll 2
    for (int cc = 0; cc < CPG; ++cc) {
        const float* fc = fb + (size_t)cc * HW;
        float acc = 0.0f;
#pragma unroll
        for (int t = 0; t < KK; ++t) {
            acc = fmaf(wgt[t], fc[offs[t]], acc);
        }
        ob[(size_t)cc * HW] = acc;
    }
}

extern "C" void kernel_launch(void* const* d_in, const int* in_sizes, int n_in,
                              void* d_out, int out_size, void* d_ws, size_t ws_size,
                              hipStream_t stream)
{
    const float* fm     = (const float*)d_in[0];
    const float* kernel = (const float*)d_in[1];
    const int*   dil    = (const int*)d_in[2];
    float*       out    = (float*)d_out;

    dim3 grid(HW / BLK, C / CPG, BS);   // 100 x 8 x 4 = 3200 blocks
    kconv_kernel<<<grid, dim3(BLK), 0, stream>>>(fm, kernel, dil, out);
}

// Round 2
// 107.571 us; speedup vs baseline: 1.5301x; 1.5301x over previous
//
#include <hip/hip_runtime.h>

#define K   5
#define KK  25
#define H   160
#define W   160
#define C   64
#define BS  4
#define HW  (H * W)
#define CPG 8           // channels per thread (grid.y = C/CPG)
#define BLK 256

// Each thread: one 4-pixel x-quad, CPG channels.
// out[b,c,y,x] = sum_{i,j} kernel[b, 24-(i*5+j), y, x] * fm[b,c,y+i-2,x+j-2] (zero pad)
__global__ __launch_bounds__(BLK) void kconv_kernel(
    const float* __restrict__ fm,
    const float* __restrict__ kern,
    const int*  __restrict__ dil,
    float* __restrict__ out)
{
    const int q  = blockIdx.x * BLK + threadIdx.x;   // quad id in [0, HW/4)
    const int b  = blockIdx.z;
    const int cg = blockIdx.y;
    const int d  = dil[0];

    const int y = q / (W / 4);
    const int x = (q - y * (W / 4)) * 4;             // quad start column (mult of 4)

    const float* fb = fm  + ((size_t)b * C + (size_t)cg * CPG) * HW;
    float*       ob = out + ((size_t)b * C + (size_t)cg * CPG) * HW + (size_t)y * W + x;
    const float* kb = kern + (size_t)b * KK * HW + (size_t)y * W + x;

    if (d == 1) {
        float acc[CPG][4];
#pragma unroll
        for (int c = 0; c < CPG; ++c)
#pragma unroll
            for (int p = 0; p < 4; ++p) acc[c][p] = 0.f;

        // Window columns x-2..x+5 as four 8B-aligned float2 loads.
        // Only the fully-OOB pair at the extreme quads gets clamped; every
        // consumer of those window slots has a zeroed weight.
        const int a_col = (x >= 2) ? (x - 2) : 0;            // clamps only at x==0
        const int d_col = (x + 4 <= W - 2) ? (x + 4) : (W - 2); // clamps only at x==W-4

#pragma unroll
        for (int i = 0; i < K; ++i) {
            const int  yy  = y + i - 2;
            const bool rok = (yy >= 0) && (yy < H);
            const int  yr  = rok ? yy : 0;

            // weights for this tap-row (flipped), zeroed where the tap is OOB
            float wrow[K][4];
#pragma unroll
            for (int j = 0; j < K; ++j) {
                const int t = i * K + j;
                const float4 wv = *(const float4*)(kb + (size_t)(KK - 1 - t) * HW);
                const float wf[4] = {wv.x, wv.y, wv.z, wv.w};
#pragma unroll
                for (int p = 0; p < 4; ++p) {
                    const int col = x + p + j - 2;
                    const bool ok = rok && (col >= 0) && (col < W);
                    wrow[j][p] = ok ? wf[p] : 0.f;
                }
            }

            const float* rowbase = fb + (size_t)yr * W;
#pragma unroll
            for (int c = 0; c < CPG; ++c) {
                const float* r = rowbase + (size_t)c * HW;
                const float2 A  = *(const float2*)(r + a_col);
                const float2 Bv = *(const float2*)(r + x);
                const float2 Cv = *(const float2*)(r + x + 2);
                const float2 Dv = *(const float2*)(r + d_col);
                const float w8[8] = {A.x, A.y, Bv.x, Bv.y, Cv.x, Cv.y, Dv.x, Dv.y};
#pragma unroll
                for (int j = 0; j < K; ++j)
#pragma unroll
                    for (int p = 0; p < 4; ++p)
                        acc[c][p] = fmaf(wrow[j][p], w8[p + j], acc[c][p]);
            }
        }

#pragma unroll
        for (int c = 0; c < CPG; ++c) {
            const float4 o = {acc[c][0], acc[c][1], acc[c][2], acc[c][3]};
            *(float4*)(ob + (size_t)c * HW) = o;
        }
    } else {
        // Generic-dilation fallback (never taken in this bench; d==1).
#pragma unroll 1
        for (int p = 0; p < 4; ++p) {
            const int xx = x + p;
            float wgt[KK];
            int   offs[KK];
#pragma unroll 1
            for (int i = 0; i < K; ++i) {
                const int  yy  = y + (i - 2) * d;
                const bool yok = (yy >= 0) && (yy < H);
                const int  yc  = min(max(yy, 0), H - 1);
#pragma unroll 1
                for (int j = 0; j < K; ++j) {
                    const int  xc = xx + (j - 2) * d;
                    const bool ok = yok && (xc >= 0) && (xc < W);
                    const int  xcc = min(max(xc, 0), W - 1);
                    const int  t  = i * K + j;
                    wgt[t]  = ok ? kb[(size_t)(KK - 1 - t) * HW + p] : 0.f;
                    offs[t] = yc * W + xcc;
                }
            }
#pragma unroll 1
            for (int c = 0; c < CPG; ++c) {
                const float* fc = fb + (size_t)c * HW;
                float a2 = 0.f;
#pragma unroll 1
                for (int t = 0; t < KK; ++t) a2 = fmaf(wgt[t], fc[offs[t]], a2);
                ob[(size_t)c * HW + p] = a2;
            }
        }
    }
}

extern "C" void kernel_launch(void* const* d_in, const int* in_sizes, int n_in,
                              void* d_out, int out_size, void* d_ws, size_t ws_size,
                              hipStream_t stream)
{
    const float* fm   = (const float*)d_in[0];
    const float* kern = (const float*)d_in[1];
    const int*   dil  = (const int*)d_in[2];
    float*       out  = (float*)d_out;

    dim3 grid(HW / 4 / BLK, C / CPG, BS);   // 25 x 8 x 4 = 800 blocks
    kconv_kernel<<<grid, dim3(BLK), 0, stream>>>(fm, kern, dil, out);
}